// Round 1
// baseline (1107.595 us; speedup 1.0000x reference)
//
#include <hip/hip_runtime.h>
#include <hip/hip_bf16.h>
#include <math.h>

#define N_CELLS 512
#define N_GENES 256
#define D 128
#define HEADS 4
#define HD 32
#define E_SP 8192
#define E_GRN 2048

// ---------------- utility ----------------

__device__ __forceinline__ float gelu_exact(float x) {
    return 0.5f * x * (1.0f + erff(x * 0.70710678118654752f));
}

template<int NT>
__device__ __forceinline__ float blockSum(float v, float* sbuf) {
    #pragma unroll
    for (int off = 32; off > 0; off >>= 1) v += __shfl_down(v, off, 64);
    int lane = threadIdx.x & 63, wid = threadIdx.x >> 6;
    __syncthreads();                 // protect sbuf from previous use
    if (lane == 0) sbuf[wid] = v;
    __syncthreads();
    float r = 0.f;
    #pragma unroll
    for (int i = 0; i < NT / 64; ++i) r += sbuf[i];
    return r;
}

// ---------------- GIN (high level) ----------------

__global__ void gin_scatter_kernel(const float* __restrict__ high,
                                   const int* __restrict__ sp,
                                   float* __restrict__ agg) {
    int tid = blockIdx.x * 256 + threadIdx.x;   // E_SP*128 total
    int e = tid >> 7, d = tid & 127;
    int src = sp[e], dst = sp[E_SP + e];
    atomicAdd(&agg[dst * D + d], high[src * D + d]);
}

__global__ __launch_bounds__(256) void gin_mlp_kernel(
    const float* __restrict__ high, const float* __restrict__ agg,
    const float* __restrict__ eps,
    const float* __restrict__ w1, const float* __restrict__ b1,
    const float* __restrict__ w2, const float* __restrict__ b2,
    const float* __restrict__ lng, const float* __restrict__ lnb,
    float* __restrict__ high_out) {
    int c = blockIdx.x;
    int t = threadIdx.x;
    __shared__ float h[D];
    __shared__ float h1[2 * D];
    __shared__ float sbuf[4];
    if (t < D) h[t] = (1.f + eps[0]) * high[c * D + t] + agg[c * D + t];
    __syncthreads();
    float a = b1[t];
    for (int k = 0; k < D; ++k) a += h[k] * w1[k * 256 + t];
    h1[t] = gelu_exact(a);
    __syncthreads();
    float x = 0.f;
    if (t < D) {
        float a2 = b2[t];
        for (int k = 0; k < 256; ++k) a2 += h1[k] * w2[k * D + t];
        x = a2;
    }
    float s = blockSum<256>(x, sbuf);
    float mean = s * (1.f / 128.f);
    float xm = (t < D) ? (x - mean) : 0.f;
    float var = blockSum<256>(xm * xm, sbuf) * (1.f / 128.f);
    if (t < D) high_out[c * D + t] = xm * rsqrtf(var + 1e-5f) * lng[t] + lnb[t];
}

// ---------------- CSR build for GRN dst segments ----------------

__global__ void csr_build_kernel(const int* __restrict__ grn,
                                 int* __restrict__ csr_off,
                                 int* __restrict__ csr_eid,
                                 int* __restrict__ csr_src) {
    __shared__ int cnt[N_GENES];
    __shared__ int off[N_GENES + 1];
    int g = threadIdx.x;
    int c = 0;
    for (int e = 0; e < E_GRN; ++e) if (grn[E_GRN + e] == g) c++;
    cnt[g] = c;
    __syncthreads();
    if (g == 0) {
        int s = 0;
        for (int i = 0; i < N_GENES; ++i) { off[i] = s; s += cnt[i]; }
        off[N_GENES] = s;
    }
    __syncthreads();
    csr_off[g] = off[g];
    if (g == 0) csr_off[N_GENES] = off[N_GENES];
    int idx = off[g];
    for (int e = 0; e < E_GRN; ++e) {
        if (grn[E_GRN + e] == g) { csr_eid[idx] = e; csr_src[idx] = grn[e]; idx++; }
    }
}

// ---------------- projection GEMM: Y = X @ W + b, K=128, N=128 per weight ----------------
// Computes two weight matrices per launch (blockIdx.y selects weight & column half)

__global__ __launch_bounds__(256) void proj_gemm_kernel(
    const float* __restrict__ X,
    const float* __restrict__ W1, const float* __restrict__ B1, float* __restrict__ Y1,
    const float* __restrict__ W2, const float* __restrict__ B2, float* __restrict__ Y2) {
    __shared__ float Xs[128][68];   // [k][row], padded for alignment+banks
    __shared__ float Ws[128][64];   // [k][col]
    int by = blockIdx.y;            // 0..3
    const float* W = (by < 2) ? W1 : W2;
    const float* B = (by < 2) ? B1 : B2;
    float* Y = (by < 2) ? Y1 : Y2;
    int colbase = (by & 1) * 64;
    int rowbase = blockIdx.x * 64;
    int t = threadIdx.x;
    {   // load X tile 64x128, store transposed
        int col4 = t & 31;
        int r0 = t >> 5;
        #pragma unroll
        for (int p = 0; p < 8; ++p) {
            int row = r0 + p * 8;
            float4 xv = *(const float4*)(X + (size_t)(rowbase + row) * 128 + col4 * 4);
            Xs[col4 * 4 + 0][row] = xv.x;
            Xs[col4 * 4 + 1][row] = xv.y;
            Xs[col4 * 4 + 2][row] = xv.z;
            Xs[col4 * 4 + 3][row] = xv.w;
        }
    }
    {   // load W tile 128x64
        int col4 = t & 15;
        int k0 = t >> 4;
        #pragma unroll
        for (int p = 0; p < 8; ++p) {
            int k = k0 + p * 16;
            *(float4*)(&Ws[k][col4 * 4]) = *(const float4*)(W + (size_t)k * 128 + colbase + col4 * 4);
        }
    }
    __syncthreads();
    int tx = t & 15, ty = t >> 4;
    float acc[4][4] = {};
    #pragma unroll 4
    for (int k = 0; k < 128; ++k) {
        float4 xv = *(const float4*)(&Xs[k][ty * 4]);
        float4 wv = *(const float4*)(&Ws[k][tx * 4]);
        float xr[4] = {xv.x, xv.y, xv.z, xv.w};
        float wr[4] = {wv.x, wv.y, wv.z, wv.w};
        #pragma unroll
        for (int i = 0; i < 4; ++i)
            #pragma unroll
            for (int j = 0; j < 4; ++j)
                acc[i][j] += xr[i] * wr[j];
    }
    float4 bv = *(const float4*)(B + colbase + tx * 4);
    float br[4] = {bv.x, bv.y, bv.z, bv.w};
    #pragma unroll
    for (int i = 0; i < 4; ++i) {
        int row = rowbase + ty * 4 + i;
        float4 o;
        o.x = acc[i][0] + br[0];
        o.y = acc[i][1] + br[1];
        o.z = acc[i][2] + br[2];
        o.w = acc[i][3] + br[3];
        *(float4*)(Y + (size_t)row * 128 + colbase + tx * 4) = o;
    }
}

// ---------------- edge attention logits: (C,E,H) layout ----------------

__global__ __launch_bounds__(256) void logits_kernel(
    const float* __restrict__ q, const float* __restrict__ k,
    const int* __restrict__ grn, float* __restrict__ logits) {
    int c = blockIdx.y;
    int eb = blockIdx.x;            // 0..31
    int t = threadIdx.x;
    int e = eb * 64 + (t >> 2);
    int h = t & 3;
    int src = grn[e], dst = grn[E_GRN + e];
    const float* qr = q + ((size_t)c * N_GENES + dst) * D + h * HD;
    const float* kr = k + ((size_t)c * N_GENES + src) * D + h * HD;
    float acc = 0.f;
    #pragma unroll
    for (int i = 0; i < 8; ++i) {
        float4 qa = *(const float4*)(qr + i * 4);
        float4 ka = *(const float4*)(kr + i * 4);
        acc += qa.x * ka.x + qa.y * ka.y + qa.z * ka.z + qa.w * ka.w;
    }
    logits[(size_t)c * (E_GRN * 4) + e * 4 + h] = acc * 0.17677669529663687f; // 1/sqrt(32)
}

// ---------------- segment softmax (in-place logits -> alpha) ----------------

__global__ __launch_bounds__(256) void softmax_kernel(
    float* __restrict__ logits,
    const int* __restrict__ csr_off, const int* __restrict__ csr_eid) {
    int c = blockIdx.x;
    int g = threadIdx.x;
    int off = csr_off[g], end = csr_off[g + 1];
    float* base = logits + (size_t)c * (E_GRN * 4);
    float m0 = -1e30f, m1 = -1e30f, m2 = -1e30f, m3 = -1e30f;
    for (int i = off; i < end; ++i) {
        float4 l = *(const float4*)(base + csr_eid[i] * 4);
        m0 = fmaxf(m0, l.x); m1 = fmaxf(m1, l.y); m2 = fmaxf(m2, l.z); m3 = fmaxf(m3, l.w);
    }
    float d0 = 0.f, d1 = 0.f, d2 = 0.f, d3 = 0.f;
    for (int i = off; i < end; ++i) {
        float4 l = *(float4*)(base + csr_eid[i] * 4);
        l.x = expf(l.x - m0); l.y = expf(l.y - m1); l.z = expf(l.z - m2); l.w = expf(l.w - m3);
        d0 += l.x; d1 += l.y; d2 += l.z; d3 += l.w;
        *(float4*)(base + csr_eid[i] * 4) = l;
    }
    float i0 = 1.f / d0, i1 = 1.f / d1, i2 = 1.f / d2, i3 = 1.f / d3;
    for (int i = off; i < end; ++i) {
        float4 l = *(float4*)(base + csr_eid[i] * 4);
        l.x *= i0; l.y *= i1; l.z *= i2; l.w *= i3;
        *(float4*)(base + csr_eid[i] * 4) = l;
    }
}

// ---------------- PV gather + skip + LayerNorm -> low_out (in d_out) ----------------

__global__ __launch_bounds__(128) void pv_ln_kernel(
    const float* __restrict__ alpha, const float* __restrict__ v,
    const int* __restrict__ csr_off, const int* __restrict__ csr_eid,
    const int* __restrict__ csr_src,
    const float* __restrict__ lng, const float* __restrict__ lnb,
    float* __restrict__ out) {
    int cg = blockIdx.x;
    int c = cg >> 8, g = cg & 255;
    int d = threadIdx.x;
    int h = d >> 5;
    float acc = out[(size_t)cg * D + d];   // skip term already there
    int off = csr_off[g], end = csr_off[g + 1];
    const float* ab = alpha + (size_t)c * (E_GRN * 4) + h;
    const float* vb = v + (size_t)c * N_GENES * D;
    for (int i = off; i < end; ++i) {
        float a = ab[csr_eid[i] * 4];
        acc += a * vb[(size_t)csr_src[i] * D + d];
    }
    __shared__ float sbuf[2];
    float s = blockSum<128>(acc, sbuf);
    float mean = s * (1.f / 128.f);
    float xm = acc - mean;
    float var = blockSum<128>(xm * xm, sbuf) * (1.f / 128.f);
    out[(size_t)cg * D + d] = xm * rsqrtf(var + 1e-5f) * lng[d] + lnb[d];
}

// ---------------- gene aggregation ----------------

__global__ __launch_bounds__(128) void gene_agg_kernel(
    const float* __restrict__ low_out,
    const float* __restrict__ agg_w, const float* __restrict__ agg_b,
    float* __restrict__ gene_agg) {
    int c = blockIdx.x, d = threadIdx.x;
    const float* base = low_out + (size_t)c * N_GENES * D;
    float s = 0.f;
    for (int g = 0; g < N_GENES; ++g) s += base[g * D + d];
    __shared__ float m[D];
    m[d] = s * (1.f / 256.f);
    __syncthreads();
    float acc = agg_b[d];
    for (int k = 0; k < D; ++k) acc += m[k] * agg_w[k * D + d];
    gene_agg[c * D + d] = gelu_exact(acc);
}

// ---------------- cross gating + high LayerNorm ----------------

__global__ __launch_bounds__(128) void cross_kernel(
    const float* __restrict__ high_emb, const float* __restrict__ high_out,
    const float* __restrict__ gene_agg,
    const float* __restrict__ cw, const float* __restrict__ cb,
    const float* __restrict__ nhg, const float* __restrict__ nhb,
    float* __restrict__ high_new, float* __restrict__ low_cross) {
    int c = blockIdx.x, d = threadIdx.x;
    __shared__ float ho[D], ga[D];
    __shared__ float sbuf[2];
    ho[d] = high_out[c * D + d];
    ga[d] = gene_agg[c * D + d];
    __syncthreads();
    float q1 = cb[0 * D + d], k1 = cb[1 * D + d], v1 = cb[2 * D + d];
    float q2 = cb[3 * D + d], k2 = cb[4 * D + d], v2 = cb[5 * D + d];
    for (int k = 0; k < D; ++k) {
        float hv = ho[k], gv = ga[k];
        q1 += hv * cw[0 * 16384 + k * D + d];
        k1 += gv * cw[1 * 16384 + k * D + d];
        v1 += gv * cw[2 * 16384 + k * D + d];
        q2 += gv * cw[3 * 16384 + k * D + d];
        k2 += hv * cw[4 * 16384 + k * D + d];
        v2 += hv * cw[5 * 16384 + k * D + d];
    }
    const float scale = 0.08838834764831845f;   // 128^-0.5
    float s1 = blockSum<128>(q1 * k1, sbuf);
    float s2 = blockSum<128>(q2 * k2, sbuf);
    float hc = (1.f / (1.f + expf(-s1 * scale))) * v1;
    float lc = (1.f / (1.f + expf(-s2 * scale))) * v2;
    low_cross[c * D + d] = lc;
    float x = high_emb[c * D + d] + ho[d] + hc;
    float sm = blockSum<128>(x, sbuf);
    float mean = sm * (1.f / 128.f);
    float xm = x - mean;
    float var = blockSum<128>(xm * xm, sbuf) * (1.f / 128.f);
    high_new[c * D + d] = xm * rsqrtf(var + 1e-5f) * nhg[d] + nhb[d];
}

// ---------------- final low LayerNorm ----------------

__global__ __launch_bounds__(128) void low_final_kernel(
    const float* __restrict__ low_emb, const float* __restrict__ low_cross,
    const float* __restrict__ nlg, const float* __restrict__ nlb,
    float* __restrict__ out) {
    int cg = blockIdx.x;
    int c = cg >> 8;
    int d = threadIdx.x;
    size_t idx = (size_t)cg * D + d;
    float x = low_emb[idx] + out[idx] + low_cross[c * D + d];
    __shared__ float sbuf[2];
    float s = blockSum<128>(x, sbuf);
    float mean = s * (1.f / 128.f);
    float xm = x - mean;
    float var = blockSum<128>(xm * xm, sbuf) * (1.f / 128.f);
    out[idx] = xm * rsqrtf(var + 1e-5f) * nlg[d] + nlb[d];
}

// ---------------- launch ----------------

extern "C" void kernel_launch(void* const* d_in, const int* in_sizes, int n_in,
                              void* d_out, int out_size, void* d_ws, size_t ws_size,
                              hipStream_t stream) {
    const float* high_emb = (const float*)d_in[0];
    const float* low_emb  = (const float*)d_in[1];
    const int*   sp       = (const int*)d_in[2];
    const int*   grn      = (const int*)d_in[3];
    const float* gin_w1   = (const float*)d_in[4];
    const float* gin_b1   = (const float*)d_in[5];
    const float* gin_w2   = (const float*)d_in[6];
    const float* gin_b2   = (const float*)d_in[7];
    const float* gin_eps  = (const float*)d_in[8];
    const float* gin_lng  = (const float*)d_in[9];
    const float* gin_lnb  = (const float*)d_in[10];
    const float* tc_wq    = (const float*)d_in[11];
    const float* tc_bq    = (const float*)d_in[12];
    const float* tc_wk    = (const float*)d_in[13];
    const float* tc_bk    = (const float*)d_in[14];
    const float* tc_wv    = (const float*)d_in[15];
    const float* tc_bv    = (const float*)d_in[16];
    const float* tc_wskip = (const float*)d_in[17];
    const float* tc_bskip = (const float*)d_in[18];
    const float* tc_lng   = (const float*)d_in[19];
    const float* tc_lnb   = (const float*)d_in[20];
    const float* cross_w  = (const float*)d_in[21];
    const float* cross_b  = (const float*)d_in[22];
    const float* agg_w    = (const float*)d_in[23];
    const float* agg_b    = (const float*)d_in[24];
    const float* nh_g     = (const float*)d_in[25];
    const float* nh_b     = (const float*)d_in[26];
    const float* nl_g     = (const float*)d_in[27];
    const float* nl_b     = (const float*)d_in[28];

    float* out = (float*)d_out;
    float* out_high = out;                       // (512,128)
    float* out_low  = out + N_CELLS * D;         // (512,256,128)

    const size_t LOW_N = (size_t)N_CELLS * N_GENES * D;  // 16777216
    float* ws_f       = (float*)d_ws;
    float* ws_qv      = ws_f;                    // q, then v
    float* ws_k       = ws_qv + LOW_N;
    float* ws_logits  = ws_k + LOW_N;            // (C, E, H) = 4194304
    float* ws_agg     = ws_logits + (size_t)N_CELLS * E_GRN * 4;
    float* ws_high_out = ws_agg + N_CELLS * D;
    float* ws_gene_agg = ws_high_out + N_CELLS * D;
    float* ws_low_cross = ws_gene_agg + N_CELLS * D;
    int* csr_off = (int*)(ws_low_cross + N_CELLS * D);
    int* csr_eid = csr_off + 260;
    int* csr_src = csr_eid + E_GRN;

    // ---- high level GIN ----
    hipMemsetAsync(ws_agg, 0, N_CELLS * D * sizeof(float), stream);
    gin_scatter_kernel<<<E_SP * D / 256, 256, 0, stream>>>(high_emb, sp, ws_agg);
    gin_mlp_kernel<<<N_CELLS, 256, 0, stream>>>(high_emb, ws_agg, gin_eps,
        gin_w1, gin_b1, gin_w2, gin_b2, gin_lng, gin_lnb, ws_high_out);

    // ---- CSR for GRN ----
    csr_build_kernel<<<1, N_GENES, 0, stream>>>(grn, csr_off, csr_eid, csr_src);

    // ---- projections: pass1 q,k ----
    proj_gemm_kernel<<<dim3(N_CELLS * N_GENES / 64, 4), 256, 0, stream>>>(
        low_emb, tc_wq, tc_bq, ws_qv, tc_wk, tc_bk, ws_k);

    // ---- logits + softmax ----
    logits_kernel<<<dim3(E_GRN / 64, N_CELLS), 256, 0, stream>>>(ws_qv, ws_k, grn, ws_logits);
    softmax_kernel<<<N_CELLS, N_GENES, 0, stream>>>(ws_logits, csr_off, csr_eid);

    // ---- projections: pass2 v (reuse q buf), skip -> out_low ----
    proj_gemm_kernel<<<dim3(N_CELLS * N_GENES / 64, 4), 256, 0, stream>>>(
        low_emb, tc_wv, tc_bv, ws_qv, tc_wskip, tc_bskip, out_low);

    // ---- PV + skip + LN -> low_out (in out_low) ----
    pv_ln_kernel<<<N_CELLS * N_GENES, 128, 0, stream>>>(
        ws_logits, ws_qv, csr_off, csr_eid, csr_src, tc_lng, tc_lnb, out_low);

    // ---- gene aggregation ----
    gene_agg_kernel<<<N_CELLS, 128, 0, stream>>>(out_low, agg_w, agg_b, ws_gene_agg);

    // ---- cross gating + high LN -> out_high ----
    cross_kernel<<<N_CELLS, 128, 0, stream>>>(high_emb, ws_high_out, ws_gene_agg,
        cross_w, cross_b, nh_g, nh_b, out_high, ws_low_cross);

    // ---- final low LN ----
    low_final_kernel<<<N_CELLS * N_GENES, 128, 0, stream>>>(
        low_emb, ws_low_cross, nl_g, nl_b, out_low);
}

// Round 3
// 545.926 us; speedup vs baseline: 2.0288x; 2.0288x over previous
//
#include <hip/hip_runtime.h>
#include <hip/hip_bf16.h>
#include <math.h>

#define N_CELLS 512
#define N_GENES 256
#define D 128
#define HEADS 4
#define HD 32
#define E_SP 8192
#define E_GRN 2048

typedef __attribute__((ext_vector_type(8))) short bf16x8;
typedef __attribute__((ext_vector_type(4))) float f32x4;

// ---------------- utility ----------------

__device__ __forceinline__ float gelu_exact(float x) {
    return 0.5f * x * (1.0f + erff(x * 0.70710678118654752f));
}

__device__ __forceinline__ unsigned short f2bf(float f) {
    unsigned u = __float_as_uint(f);
    return (unsigned short)((u + 0x7FFFu + ((u >> 16) & 1u)) >> 16);
}

__device__ __forceinline__ float blo(unsigned u) { return __uint_as_float(u << 16); }
__device__ __forceinline__ float bhi(unsigned u) { return __uint_as_float(u & 0xFFFF0000u); }
__device__ __forceinline__ float bdot(unsigned a, unsigned b) {
    return blo(a) * blo(b) + bhi(a) * bhi(b);
}

template<int NT>
__device__ __forceinline__ float blockSum(float v, float* sbuf) {
    #pragma unroll
    for (int off = 32; off > 0; off >>= 1) v += __shfl_down(v, off, 64);
    int lane = threadIdx.x & 63, wid = threadIdx.x >> 6;
    __syncthreads();
    if (lane == 0) sbuf[wid] = v;
    __syncthreads();
    float r = 0.f;
    #pragma unroll
    for (int i = 0; i < NT / 64; ++i) r += sbuf[i];
    return r;
}

// ---------------- GIN (high level) ----------------

__global__ void gin_scatter_kernel(const float* __restrict__ high,
                                   const int* __restrict__ sp,
                                   float* __restrict__ agg) {
    int tid = blockIdx.x * 256 + threadIdx.x;
    int e = tid >> 7, d = tid & 127;
    int src = sp[e], dst = sp[E_SP + e];
    atomicAdd(&agg[dst * D + d], high[src * D + d]);
}

__global__ __launch_bounds__(256) void gin_mlp_kernel(
    const float* __restrict__ high, const float* __restrict__ agg,
    const float* __restrict__ eps,
    const float* __restrict__ w1, const float* __restrict__ b1,
    const float* __restrict__ w2, const float* __restrict__ b2,
    const float* __restrict__ lng, const float* __restrict__ lnb,
    float* __restrict__ high_out) {
    int c = blockIdx.x;
    int t = threadIdx.x;
    __shared__ float h[D];
    __shared__ float h1[2 * D];
    __shared__ float sbuf[4];
    if (t < D) h[t] = (1.f + eps[0]) * high[c * D + t] + agg[c * D + t];
    __syncthreads();
    float a = b1[t];
    for (int k = 0; k < D; ++k) a += h[k] * w1[k * 256 + t];
    h1[t] = gelu_exact(a);
    __syncthreads();
    float x = 0.f;
    if (t < D) {
        float a2 = b2[t];
        for (int k = 0; k < 256; ++k) a2 += h1[k] * w2[k * D + t];
        x = a2;
    }
    float s = blockSum<256>(x, sbuf);
    float mean = s * (1.f / 128.f);
    float xm = (t < D) ? (x - mean) : 0.f;
    float var = blockSum<256>(xm * xm, sbuf) * (1.f / 128.f);
    if (t < D) high_out[c * D + t] = xm * rsqrtf(var + 1e-5f) * lng[t] + lnb[t];
}

// ---------------- CSR build (parallel histogram + scan + fill) ----------------

__global__ __launch_bounds__(256) void csr_build_kernel(
    const int* __restrict__ grn,
    int* __restrict__ csr_off, int* __restrict__ csr_eid, int* __restrict__ csr_src) {
    __shared__ int cnt[N_GENES];
    __shared__ int scan[N_GENES];
    __shared__ int cur[N_GENES];
    int t = threadIdx.x;
    cnt[t] = 0;
    __syncthreads();
    for (int e = t; e < E_GRN; e += 256) atomicAdd(&cnt[grn[E_GRN + e]], 1);
    __syncthreads();
    scan[t] = cnt[t];
    __syncthreads();
    #pragma unroll
    for (int s = 1; s < 256; s <<= 1) {
        int v = (t >= s) ? scan[t - s] : 0;
        __syncthreads();
        scan[t] += v;
        __syncthreads();
    }
    int excl = scan[t] - cnt[t];
    csr_off[t] = excl;
    if (t == 255) csr_off[256] = scan[255];
    cur[t] = excl;
    __syncthreads();
    for (int e = t; e < E_GRN; e += 256) {
        int dst = grn[E_GRN + e];
        int pos = atomicAdd(&cur[dst], 1);
        csr_eid[pos] = e;
        csr_src[pos] = grn[e];
    }
}

// ---------------- weight transpose + bf16 cast: Wt[w][n][k] ----------------

__global__ __launch_bounds__(256) void wt_kernel(
    const float* __restrict__ wq, const float* __restrict__ wk,
    const float* __restrict__ wv, const float* __restrict__ wskip,
    unsigned short* __restrict__ wt4) {
    __shared__ float tile[128][132];
    int w = blockIdx.x;
    const float* Wp = (w == 0) ? wq : (w == 1) ? wk : (w == 2) ? wv : wskip;
    int t = threadIdx.x;
    #pragma unroll
    for (int rep = 0; rep < 16; ++rep) {
        int f4 = rep * 256 + t;
        float4 v = ((const float4*)Wp)[f4];
        int f = f4 * 4;
        int k = f >> 7, n = f & 127;
        tile[k][n] = v.x; tile[k][n + 1] = v.y; tile[k][n + 2] = v.z; tile[k][n + 3] = v.w;
    }
    __syncthreads();
    unsigned short* out = wt4 + (size_t)w * 16384;
    #pragma unroll
    for (int rep = 0; rep < 16; ++rep) {
        int f4 = rep * 256 + t;
        int f = f4 * 4;
        int n = f >> 7, k = f & 127;
        ushort4 o;
        o.x = f2bf(tile[k][n]);
        o.y = f2bf(tile[k + 1][n]);
        o.z = f2bf(tile[k + 2][n]);
        o.w = f2bf(tile[k + 3][n]);
        *(ushort4*)(out + (size_t)n * 128 + k) = o;
    }
}

// ---------------- fused 4-weight MFMA projection ----------------
// X (f32, M x 128) @ W{q,k,v,skip} (128x128) + b  ->  q,k,v (bf16), skip (f32)

__global__ __launch_bounds__(256, 2) void proj4_kernel(
    const float* __restrict__ X,
    const unsigned short* __restrict__ Wt4,
    const float* __restrict__ bq, const float* __restrict__ bk,
    const float* __restrict__ bv, const float* __restrict__ bs,
    unsigned short* __restrict__ Yq, unsigned short* __restrict__ Yk,
    unsigned short* __restrict__ Yv, float* __restrict__ Yskip) {
    __shared__ short Xs[128 * 128];
    __shared__ short Ws[128 * 128];
    int t = threadIdx.x;
    int lane = t & 63, wid = t >> 6;
    const float* Xblk = X + (size_t)blockIdx.x * 128 * 128;

    // stage X tile (f32 -> bf16, XOR-swizzled rows)
    #pragma unroll
    for (int rep = 0; rep < 16; ++rep) {
        int f4 = rep * 256 + t;
        float4 xv = ((const float4*)Xblk)[f4];
        int f = f4 * 4;
        int row = f >> 7, k = f & 127;
        unsigned p0 = (unsigned)f2bf(xv.x) | ((unsigned)f2bf(xv.y) << 16);
        unsigned p1 = (unsigned)f2bf(xv.z) | ((unsigned)f2bf(xv.w) << 16);
        int eidx = (row * 128 + k) ^ ((row & 7) << 3);
        *(uint2*)(&Xs[eidx]) = make_uint2(p0, p1);
    }

    const float* Bs_[4] = {bq, bk, bv, bs};
    int lr = lane & 15, lg = lane >> 4;
    int rbase = (wid >> 1) * 64, cbase = (wid & 1) * 64;
    int orow0 = blockIdx.x * 128 + rbase;

    for (int w = 0; w < 4; ++w) {
        __syncthreads();   // previous compute done (and X staging on w==0)
        const uint2* Wsrc = (const uint2*)(Wt4 + (size_t)w * 16384);
        #pragma unroll
        for (int rep = 0; rep < 16; ++rep) {
            int e4 = rep * 256 + t;
            uint2 d2 = Wsrc[e4];
            int f = e4 * 4;
            int n = f >> 7, k = f & 127;
            *(uint2*)(&Ws[(n * 128 + k) ^ ((n & 7) << 3)]) = d2;
        }
        __syncthreads();

        f32x4 acc[4][4] = {};
        #pragma unroll
        for (int ks = 0; ks < 4; ++ks) {
            int k0 = ks * 32 + lg * 8;
            bf16x8 a[4], b[4];
            #pragma unroll
            for (int m = 0; m < 4; ++m) {
                int row = rbase + m * 16 + lr;
                a[m] = *(const bf16x8*)(&Xs[(row * 128 + k0) ^ ((row & 7) << 3)]);
            }
            #pragma unroll
            for (int n = 0; n < 4; ++n) {
                int col = cbase + n * 16 + lr;
                b[n] = *(const bf16x8*)(&Ws[(col * 128 + k0) ^ ((col & 7) << 3)]);
            }
            #pragma unroll
            for (int m = 0; m < 4; ++m)
                #pragma unroll
                for (int n = 0; n < 4; ++n)
                    acc[m][n] = __builtin_amdgcn_mfma_f32_16x16x32_bf16(a[m], b[n], acc[m][n], 0, 0, 0);
        }

        const float* Bb = Bs_[w];
        if (w < 3) {
            unsigned short* Y = (w == 0) ? Yq : (w == 1) ? Yk : Yv;
            #pragma unroll
            for (int n = 0; n < 4; ++n) {
                int col = cbase + n * 16 + lr;
                float bias = Bb[col];
                #pragma unroll
                for (int m = 0; m < 4; ++m)
                    #pragma unroll
                    for (int j = 0; j < 4; ++j) {
                        int row = orow0 + m * 16 + lg * 4 + j;
                        Y[(size_t)row * 128 + col] = f2bf(acc[m][n][j] + bias);
                    }
            }
        } else {
            #pragma unroll
            for (int n = 0; n < 4; ++n) {
                int col = cbase + n * 16 + lr;
                float bias = Bb[col];
                #pragma unroll
                for (int m = 0; m < 4; ++m)
                    #pragma unroll
                    for (int j = 0; j < 4; ++j) {
                        int row = orow0 + m * 16 + lg * 4 + j;
                        Yskip[(size_t)row * 128 + col] = acc[m][n][j] + bias;
                    }
            }
        }
    }
}

// ---------------- edge attention logits (bf16 q/k) ----------------

__global__ __launch_bounds__(256) void logits_kernel(
    const unsigned short* __restrict__ q, const unsigned short* __restrict__ k,
    const int* __restrict__ grn, float* __restrict__ logits) {
    int c = blockIdx.y;
    int eb = blockIdx.x;
    int t = threadIdx.x;
    int e = eb * 64 + (t >> 2);
    int h = t & 3;
    int src = grn[e], dst = grn[E_GRN + e];
    const unsigned short* qr = q + ((size_t)c * N_GENES + dst) * D + h * HD;
    const unsigned short* kr = k + ((size_t)c * N_GENES + src) * D + h * HD;
    float acc = 0.f;
    #pragma unroll
    for (int i = 0; i < 4; ++i) {
        uint4 qa = *(const uint4*)(qr + i * 8);
        uint4 ka = *(const uint4*)(kr + i * 8);
        acc += bdot(qa.x, ka.x) + bdot(qa.y, ka.y) + bdot(qa.z, ka.z) + bdot(qa.w, ka.w);
    }
    logits[(size_t)c * (E_GRN * 4) + e * 4 + h] = acc * 0.17677669529663687f;
}

// ---------------- segment softmax (in-place) ----------------

__global__ __launch_bounds__(256) void softmax_kernel(
    float* __restrict__ logits,
    const int* __restrict__ csr_off, const int* __restrict__ csr_eid) {
    int c = blockIdx.x;
    int g = threadIdx.x;
    int off = csr_off[g], end = csr_off[g + 1];
    float* base = logits + (size_t)c * (E_GRN * 4);
    float m0 = -1e30f, m1 = -1e30f, m2 = -1e30f, m3 = -1e30f;
    for (int i = off; i < end; ++i) {
        float4 l = *(const float4*)(base + csr_eid[i] * 4);
        m0 = fmaxf(m0, l.x); m1 = fmaxf(m1, l.y); m2 = fmaxf(m2, l.z); m3 = fmaxf(m3, l.w);
    }
    float d0 = 0.f, d1 = 0.f, d2 = 0.f, d3 = 0.f;
    for (int i = off; i < end; ++i) {
        float4 l = *(float4*)(base + csr_eid[i] * 4);
        l.x = expf(l.x - m0); l.y = expf(l.y - m1); l.z = expf(l.z - m2); l.w = expf(l.w - m3);
        d0 += l.x; d1 += l.y; d2 += l.z; d3 += l.w;
        *(float4*)(base + csr_eid[i] * 4) = l;
    }
    float i0 = 1.f / d0, i1 = 1.f / d1, i2 = 1.f / d2, i3 = 1.f / d3;
    for (int i = off; i < end; ++i) {
        float4 l = *(float4*)(base + csr_eid[i] * 4);
        l.x *= i0; l.y *= i1; l.z *= i2; l.w *= i3;
        *(float4*)(base + csr_eid[i] * 4) = l;
    }
}

// ---------------- PV gather + skip + LayerNorm ----------------

__global__ __launch_bounds__(128) void pv_ln_kernel(
    const float* __restrict__ alpha, const unsigned short* __restrict__ v,
    const int* __restrict__ csr_off, const int* __restrict__ csr_eid,
    const int* __restrict__ csr_src,
    const float* __restrict__ lng, const float* __restrict__ lnb,
    float* __restrict__ out) {
    int cg = blockIdx.x;
    int c = cg >> 8, g = cg & 255;
    int d = threadIdx.x;
    int h = d >> 5;
    float acc = out[(size_t)cg * D + d];   // skip term already there
    int off = csr_off[g], end = csr_off[g + 1];
    const float* ab = alpha + (size_t)c * (E_GRN * 4) + h;
    const unsigned short* vb = v + (size_t)c * N_GENES * D;
    for (int i = off; i < end; ++i) {
        float a = ab[csr_eid[i] * 4];
        acc += a * __uint_as_float((unsigned)vb[(size_t)csr_src[i] * D + d] << 16);
    }
    __shared__ float sbuf[2];
    float s = blockSum<128>(acc, sbuf);
    float mean = s * (1.f / 128.f);
    float xm = acc - mean;
    float var = blockSum<128>(xm * xm, sbuf) * (1.f / 128.f);
    out[(size_t)cg * D + d] = xm * rsqrtf(var + 1e-5f) * lng[d] + lnb[d];
}

// ---------------- gene aggregation ----------------

__global__ __launch_bounds__(128) void gene_agg_kernel(
    const float* __restrict__ low_out,
    const float* __restrict__ agg_w, const float* __restrict__ agg_b,
    float* __restrict__ gene_agg) {
    int c = blockIdx.x, d = threadIdx.x;
    const float* base = low_out + (size_t)c * N_GENES * D;
    float s = 0.f;
    for (int g = 0; g < N_GENES; ++g) s += base[g * D + d];
    __shared__ float m[D];
    m[d] = s * (1.f / 256.f);
    __syncthreads();
    float acc = agg_b[d];
    for (int k = 0; k < D; ++k) acc += m[k] * agg_w[k * D + d];
    gene_agg[c * D + d] = gelu_exact(acc);
}

// ---------------- cross gating + high LayerNorm ----------------

__global__ __launch_bounds__(128) void cross_kernel(
    const float* __restrict__ high_emb, const float* __restrict__ high_out,
    const float* __restrict__ gene_agg,
    const float* __restrict__ cw, const float* __restrict__ cb,
    const float* __restrict__ nhg, const float* __restrict__ nhb,
    float* __restrict__ high_new, float* __restrict__ low_cross) {
    int c = blockIdx.x, d = threadIdx.x;
    __shared__ float ho[D], ga[D];
    __shared__ float sbuf[2];
    ho[d] = high_out[c * D + d];
    ga[d] = gene_agg[c * D + d];
    __syncthreads();
    float q1 = cb[0 * D + d], k1 = cb[1 * D + d], v1 = cb[2 * D + d];
    float q2 = cb[3 * D + d], k2 = cb[4 * D + d], v2 = cb[5 * D + d];
    for (int k = 0; k < D; ++k) {
        float hv = ho[k], gv = ga[k];
        q1 += hv * cw[0 * 16384 + k * D + d];
        k1 += gv * cw[1 * 16384 + k * D + d];
        v1 += gv * cw[2 * 16384 + k * D + d];
        q2 += gv * cw[3 * 16384 + k * D + d];
        k2 += hv * cw[4 * 16384 + k * D + d];
        v2 += hv * cw[5 * 16384 + k * D + d];
    }
    const float scale = 0.08838834764831845f;
    float s1 = blockSum<128>(q1 * k1, sbuf);
    float s2 = blockSum<128>(q2 * k2, sbuf);
    float hc = (1.f / (1.f + expf(-s1 * scale))) * v1;
    float lc = (1.f / (1.f + expf(-s2 * scale))) * v2;
    low_cross[c * D + d] = lc;
    float x = high_emb[c * D + d] + ho[d] + hc;
    float sm = blockSum<128>(x, sbuf);
    float mean = sm * (1.f / 128.f);
    float xm = x - mean;
    float var = blockSum<128>(xm * xm, sbuf) * (1.f / 128.f);
    high_new[c * D + d] = xm * rsqrtf(var + 1e-5f) * nhg[d] + nhb[d];
}

// ---------------- final low LayerNorm ----------------

__global__ __launch_bounds__(128) void low_final_kernel(
    const float* __restrict__ low_emb, const float* __restrict__ low_cross,
    const float* __restrict__ nlg, const float* __restrict__ nlb,
    float* __restrict__ out) {
    int cg = blockIdx.x;
    int c = cg >> 8;
    int d = threadIdx.x;
    size_t idx = (size_t)cg * D + d;
    float x = low_emb[idx] + out[idx] + low_cross[c * D + d];
    __shared__ float sbuf[2];
    float s = blockSum<128>(x, sbuf);
    float mean = s * (1.f / 128.f);
    float xm = x - mean;
    float var = blockSum<128>(xm * xm, sbuf) * (1.f / 128.f);
    out[idx] = xm * rsqrtf(var + 1e-5f) * nlg[d] + nlb[d];
}

// ---------------- launch ----------------

extern "C" void kernel_launch(void* const* d_in, const int* in_sizes, int n_in,
                              void* d_out, int out_size, void* d_ws, size_t ws_size,
                              hipStream_t stream) {
    const float* high_emb = (const float*)d_in[0];
    const float* low_emb  = (const float*)d_in[1];
    const int*   sp       = (const int*)d_in[2];
    const int*   grn      = (const int*)d_in[3];
    const float* gin_w1   = (const float*)d_in[4];
    const float* gin_b1   = (const float*)d_in[5];
    const float* gin_w2   = (const float*)d_in[6];
    const float* gin_b2   = (const float*)d_in[7];
    const float* gin_eps  = (const float*)d_in[8];
    const float* gin_lng  = (const float*)d_in[9];
    const float* gin_lnb  = (const float*)d_in[10];
    const float* tc_wq    = (const float*)d_in[11];
    const float* tc_bq    = (const float*)d_in[12];
    const float* tc_wk    = (const float*)d_in[13];
    const float* tc_bk    = (const float*)d_in[14];
    const float* tc_wv    = (const float*)d_in[15];
    const float* tc_bv    = (const float*)d_in[16];
    const float* tc_wskip = (const float*)d_in[17];
    const float* tc_bskip = (const float*)d_in[18];
    const float* tc_lng   = (const float*)d_in[19];
    const float* tc_lnb   = (const float*)d_in[20];
    const float* cross_w  = (const float*)d_in[21];
    const float* cross_b  = (const float*)d_in[22];
    const float* agg_w    = (const float*)d_in[23];
    const float* agg_b    = (const float*)d_in[24];
    const float* nh_g     = (const float*)d_in[25];
    const float* nh_b     = (const float*)d_in[26];
    const float* nl_g     = (const float*)d_in[27];
    const float* nl_b     = (const float*)d_in[28];

    float* out = (float*)d_out;
    float* out_high = out;
    float* out_low  = out + N_CELLS * D;

    const size_t LOW_N = (size_t)N_CELLS * N_GENES * D;   // 16777216

    unsigned short* q_b = (unsigned short*)d_ws;
    unsigned short* k_b = q_b + LOW_N;
    unsigned short* v_b = k_b + LOW_N;
    float* ws_logits    = (float*)(v_b + LOW_N);
    float* ws_agg       = ws_logits + (size_t)N_CELLS * E_GRN * HEADS;
    float* ws_high_out  = ws_agg + N_CELLS * D;
    float* ws_gene_agg  = ws_high_out + N_CELLS * D;
    float* ws_low_cross = ws_gene_agg + N_CELLS * D;
    unsigned short* wt4 = (unsigned short*)(ws_low_cross + N_CELLS * D);
    int* csr_off = (int*)(wt4 + 4 * 128 * 128);
    int* csr_eid = csr_off + 260;
    int* csr_src = csr_eid + E_GRN;

    // high level GIN
    hipMemsetAsync(ws_agg, 0, N_CELLS * D * sizeof(float), stream);
    gin_scatter_kernel<<<E_SP * D / 256, 256, 0, stream>>>(high_emb, sp, ws_agg);
    gin_mlp_kernel<<<N_CELLS, 256, 0, stream>>>(high_emb, ws_agg, gin_eps,
        gin_w1, gin_b1, gin_w2, gin_b2, gin_lng, gin_lnb, ws_high_out);

    // CSR + weight transpose (small, independent)
    csr_build_kernel<<<1, N_GENES, 0, stream>>>(grn, csr_off, csr_eid, csr_src);
    wt_kernel<<<4, 256, 0, stream>>>(tc_wq, tc_wk, tc_wv, tc_wskip, wt4);

    // fused 4-weight projection (MFMA)
    proj4_kernel<<<N_CELLS * N_GENES / 128, 256, 0, stream>>>(
        low_emb, wt4, tc_bq, tc_bk, tc_bv, tc_bskip, q_b, k_b, v_b, out_low);

    // logits + softmax
    logits_kernel<<<dim3(E_GRN / 64, N_CELLS), 256, 0, stream>>>(q_b, k_b, grn, ws_logits);
    softmax_kernel<<<N_CELLS, N_GENES, 0, stream>>>(ws_logits, csr_off, csr_eid);

    // PV + skip + LN
    pv_ln_kernel<<<N_CELLS * N_GENES, 128, 0, stream>>>(
        ws_logits, v_b, csr_off, csr_eid, csr_src, tc_lng, tc_lnb, out_low);

    // gene aggregation
    gene_agg_kernel<<<N_CELLS, 128, 0, stream>>>(out_low, agg_w, agg_b, ws_gene_agg);

    // cross gating + high LN
    cross_kernel<<<N_CELLS, 128, 0, stream>>>(high_emb, ws_high_out, ws_gene_agg,
        cross_w, cross_b, nh_g, nh_b, out_high, ws_low_cross);

    // final low LN
    low_final_kernel<<<N_CELLS * N_GENES, 128, 0, stream>>>(
        low_emb, ws_low_cross, nl_g, nl_b, out_low);
}